// Round 9
// baseline (1032.264 us; speedup 1.0000x reference)
//
#include <hip/hip_runtime.h>
#include <hip/hip_bf16.h>
#include <stdint.h>

typedef __bf16 bf16;
typedef __bf16 bf16x8 __attribute__((ext_vector_type(8)));
typedef float  f32x4v __attribute__((ext_vector_type(4)));

__device__ __forceinline__ void cvt8(const float* v, bf16x8& hh, bf16x8& ll) {
    #pragma unroll
    for (int j = 0; j < 8; j++) {
        bf16 b = (bf16)v[j]; hh[j] = b; ll[j] = (bf16)(v[j] - (float)b);
    }
}

// ---------------------------------------------------------------- reductions
__device__ __forceinline__ float block_reduce_sum256(float v) {
    __shared__ float red[256];
    int tid = threadIdx.x;
    red[tid] = v; __syncthreads();
    #pragma unroll
    for (int s = 128; s > 0; s >>= 1) {
        if (tid < s) red[tid] += red[tid + s];
        __syncthreads();
    }
    float r = red[0]; __syncthreads();
    return r;
}

// ---------------------------------------------------------------- bf16x3 split-MFMA GEMM
template<int BMT, bool RELU, bool TRANS, bool BNAT, bool HILO>
__global__ __launch_bounds__(256, 2)
void gemm3(const float* __restrict__ A, const float* __restrict__ B,
           const float* __restrict__ bias, float* __restrict__ C,
           bf16* __restrict__ Chi, bf16* __restrict__ Clo,
           int K, int lda, int ldb, int ldc, float alpha)
{
    constexpr int BN = 128, TK = 32;
    constexpr int RM = BMT / 32;
    __shared__ __align__(16) bf16 Ah[BMT * TK];
    __shared__ __align__(16) bf16 Al[BMT * TK];
    __shared__ __align__(16) bf16 Bh[BN * TK];
    __shared__ __align__(16) bf16 Bl[BN * TK];

    const int tid  = threadIdx.x;
    const int wave = tid >> 6, lane = tid & 63;
    const int wr = wave >> 1, wc = wave & 1;
    const long bm = (long)blockIdx.y * BMT;
    const long bn = (long)blockIdx.x * BN;
    const int fr = lane & 15, fq = lane >> 4;

    f32x4v acc[RM][4] = {};

    for (int k0 = 0; k0 < K; k0 += TK) {
        #pragma unroll
        for (int it = 0; it < BMT / 64; it++) {
            const int c = it * 256 + tid;
            const int r = c >> 2, k8 = c & 3;
            const float* src = A + (bm + r) * (long)lda + k0 + k8 * 8;
            float4 f0 = ((const float4*)src)[0], f1 = ((const float4*)src)[1];
            float v[8] = {f0.x, f0.y, f0.z, f0.w, f1.x, f1.y, f1.z, f1.w};
            bf16x8 hh, ll; cvt8(v, hh, ll);
            *(bf16x8*)&Ah[r * TK + k8 * 8] = hh;
            *(bf16x8*)&Al[r * TK + k8 * 8] = ll;
        }
        if (BNAT) {
            const int col = tid & 127, bkh = (tid >> 7) * 16;
            const float* src = B + (long)(k0 + bkh) * ldb + bn + col;
            float v[16];
            #pragma unroll
            for (int kk = 0; kk < 16; kk++) v[kk] = src[(long)kk * ldb];
            bf16x8 h0, l0, h1, l1; cvt8(v, h0, l0); cvt8(v + 8, h1, l1);
            bf16* hd = &Bh[col * TK + bkh];
            bf16* ld_ = &Bl[col * TK + bkh];
            ((bf16x8*)hd)[0] = h0; ((bf16x8*)hd)[1] = h1;
            ((bf16x8*)ld_)[0] = l0; ((bf16x8*)ld_)[1] = l1;
        } else {
            #pragma unroll
            for (int it = 0; it < 2; it++) {
                const int c = it * 256 + tid;
                const int r = c >> 2, k8 = c & 3;
                const float* src = B + (bn + r) * (long)ldb + k0 + k8 * 8;
                float4 f0 = ((const float4*)src)[0], f1 = ((const float4*)src)[1];
                float v[8] = {f0.x, f0.y, f0.z, f0.w, f1.x, f1.y, f1.z, f1.w};
                bf16x8 hh, ll; cvt8(v, hh, ll);
                *(bf16x8*)&Bh[r * TK + k8 * 8] = hh;
                *(bf16x8*)&Bl[r * TK + k8 * 8] = ll;
            }
        }
        __syncthreads();

        bf16x8 ah[RM], am[RM], bh[4], bm_[4];
        #pragma unroll
        for (int i = 0; i < RM; i++) {
            const int r = (wr * (BMT / 2) + i * 16 + fr) * TK + fq * 8;
            ah[i] = *(const bf16x8*)&Ah[r];
            am[i] = *(const bf16x8*)&Al[r];
        }
        #pragma unroll
        for (int j = 0; j < 4; j++) {
            const int r = (wc * 64 + j * 16 + fr) * TK + fq * 8;
            bh[j] = *(const bf16x8*)&Bh[r];
            bm_[j] = *(const bf16x8*)&Bl[r];
        }
        #pragma unroll
        for (int i = 0; i < RM; i++)
            #pragma unroll
            for (int j = 0; j < 4; j++) {
                acc[i][j] = __builtin_amdgcn_mfma_f32_16x16x32_bf16(am[i], bh[j], acc[i][j], 0, 0, 0);
                acc[i][j] = __builtin_amdgcn_mfma_f32_16x16x32_bf16(ah[i], bm_[j], acc[i][j], 0, 0, 0);
                acc[i][j] = __builtin_amdgcn_mfma_f32_16x16x32_bf16(ah[i], bh[j], acc[i][j], 0, 0, 0);
            }
        __syncthreads();
    }

    #pragma unroll
    for (int i = 0; i < RM; i++) {
        #pragma unroll
        for (int j = 0; j < 4; j++) {
            const long col = bn + wc * 64 + j * 16 + fr;
            const float bv = bias ? bias[col] : 0.f;
            #pragma unroll
            for (int r = 0; r < 4; r++) {
                const long row = bm + wr * (BMT / 2) + i * 16 + fq * 4 + r;
                float v = acc[i][j][r] * alpha + bv;
                if (RELU) v = fmaxf(v, 0.f);
                const long idx = TRANS ? (col * (long)ldc + row) : (row * (long)ldc + col);
                if (HILO) {
                    bf16 hh = (bf16)v;
                    Chi[idx] = hh;
                    Clo[idx] = (bf16)(v - (float)hh);
                } else {
                    C[idx] = v;
                }
            }
        }
    }
}

// ---------------------------------------------------------------- fused QKV projection
// x [4096][512] f32; wq/wk/wv natural [512][512]; q -> f32, k -> hi/lo,
// v -> hi/lo transposed [512][4096]. Grid (12, 64): blockIdx.x selects
// weight (x/4) and 128-col block (x%4). BM=64 tile.
__global__ __launch_bounds__(256, 2)
void qkv_gemm(const float* __restrict__ X,
              const float* __restrict__ Wq, const float* __restrict__ Wk, const float* __restrict__ Wv,
              const float* __restrict__ Bq, const float* __restrict__ Bk, const float* __restrict__ Bv,
              float* __restrict__ Qo, bf16* __restrict__ Khi, bf16* __restrict__ Klo,
              bf16* __restrict__ Vthi, bf16* __restrict__ Vtlo)
{
    constexpr int TK = 32, D = 512, N = 4096;
    __shared__ __align__(16) bf16 Ah[64 * TK];
    __shared__ __align__(16) bf16 Al[64 * TK];
    __shared__ __align__(16) bf16 Bh[128 * TK];
    __shared__ __align__(16) bf16 Bl[128 * TK];

    const int tid  = threadIdx.x;
    const int wave = tid >> 6, lane = tid & 63;
    const int wr = wave >> 1, wc = wave & 1;
    const int sel = blockIdx.x >> 2, wcol0 = (blockIdx.x & 3) * 128;
    const long bm = (long)blockIdx.y * 64;
    const int fr = lane & 15, fq = lane >> 4;

    const float* W  = sel == 0 ? Wq : (sel == 1 ? Wk : Wv);
    const float* Bb = sel == 0 ? Bq : (sel == 1 ? Bk : Bv);

    f32x4v acc[2][4] = {};

    for (int k0 = 0; k0 < D; k0 += TK) {
        {
            const int r = tid >> 2, k8 = tid & 3;
            const float* src = X + (bm + r) * (long)D + k0 + k8 * 8;
            float4 f0 = ((const float4*)src)[0], f1 = ((const float4*)src)[1];
            float v[8] = {f0.x, f0.y, f0.z, f0.w, f1.x, f1.y, f1.z, f1.w};
            bf16x8 hh, ll; cvt8(v, hh, ll);
            *(bf16x8*)&Ah[r * TK + k8 * 8] = hh;
            *(bf16x8*)&Al[r * TK + k8 * 8] = ll;
        }
        {
            const int col = tid & 127, bkh = (tid >> 7) * 16;
            const float* src = W + (long)(k0 + bkh) * D + wcol0 + col;
            float v[16];
            #pragma unroll
            for (int kk = 0; kk < 16; kk++) v[kk] = src[(long)kk * D];
            bf16x8 h0, l0, h1, l1; cvt8(v, h0, l0); cvt8(v + 8, h1, l1);
            bf16* hd = &Bh[col * TK + bkh];
            bf16* ld_ = &Bl[col * TK + bkh];
            ((bf16x8*)hd)[0] = h0; ((bf16x8*)hd)[1] = h1;
            ((bf16x8*)ld_)[0] = l0; ((bf16x8*)ld_)[1] = l1;
        }
        __syncthreads();

        bf16x8 ah[2], am[2], bh[4], bm_[4];
        #pragma unroll
        for (int i = 0; i < 2; i++) {
            const int r = (wr * 32 + i * 16 + fr) * TK + fq * 8;
            ah[i] = *(const bf16x8*)&Ah[r];
            am[i] = *(const bf16x8*)&Al[r];
        }
        #pragma unroll
        for (int j = 0; j < 4; j++) {
            const int r = (wc * 64 + j * 16 + fr) * TK + fq * 8;
            bh[j] = *(const bf16x8*)&Bh[r];
            bm_[j] = *(const bf16x8*)&Bl[r];
        }
        #pragma unroll
        for (int i = 0; i < 2; i++)
            #pragma unroll
            for (int j = 0; j < 4; j++) {
                acc[i][j] = __builtin_amdgcn_mfma_f32_16x16x32_bf16(am[i], bh[j], acc[i][j], 0, 0, 0);
                acc[i][j] = __builtin_amdgcn_mfma_f32_16x16x32_bf16(ah[i], bm_[j], acc[i][j], 0, 0, 0);
                acc[i][j] = __builtin_amdgcn_mfma_f32_16x16x32_bf16(ah[i], bh[j], acc[i][j], 0, 0, 0);
            }
        __syncthreads();
    }

    #pragma unroll
    for (int i = 0; i < 2; i++) {
        #pragma unroll
        for (int j = 0; j < 4; j++) {
            const int col = wc * 64 + j * 16 + fr;        // 0..127
            const float bv = Bb[wcol0 + col];
            #pragma unroll
            for (int r = 0; r < 4; r++) {
                const long row = bm + wr * 32 + i * 16 + fq * 4 + r;
                const float v = acc[i][j][r] + bv;
                if (sel == 0) {
                    Qo[row * D + wcol0 + col] = v;
                } else {
                    const bf16 hh = (bf16)v;
                    const bf16 ll = (bf16)(v - (float)hh);
                    const long idx = (sel == 1) ? (row * (long)D + wcol0 + col)
                                                : ((long)(wcol0 + col) * N + row);
                    if (sel == 1) { Khi[idx] = hh; Klo[idx] = ll; }
                    else          { Vthi[idx] = hh; Vtlo[idx] = ll; }
                }
            }
        }
    }
}

// ---------------------------------------------------------------- fused flash attention (KV-split x4, 32-row KV tiles)
// Block = (qt, h, s): 64 Q-rows, head h, KV range [s*1024, s*1024+1024).
// LDS 36 KB -> 4 blocks/CU. Each wave owns 16 S rows (no cross-wave softmax).
__global__ __launch_bounds__(256, 4)
void flash_attn(const float* __restrict__ Q,
                const bf16* __restrict__ Khi, const bf16* __restrict__ Klo,
                const bf16* __restrict__ Vthi, const bf16* __restrict__ Vtlo,
                float* __restrict__ Op, float* __restrict__ ml)
{
    constexpr int N = 4096, D = 512, SPAN = 1024;
    constexpr float TS = 0.12751791f;   // (1/sqrt(128)) * log2(e)
    constexpr int VSTR = 40, PSTR = 40;

    __shared__ __align__(16) bf16 smem[18432];   // 36 KB
    bf16* Kh = smem;                  // [32][128] xor-swizzled
    bf16* Kl = smem + 4096;
    bf16* Vh = smem + 8192;           // [128][40] padded
    bf16* Vl = smem + 13312;

    const int tid = threadIdx.x;
    const int wave = tid >> 6, lane = tid & 63;
    const int fr = lane & 15, fq = lane >> 4;
    const int qt = blockIdx.x, h = blockIdx.y, s = blockIdx.z;
    const long q0 = (long)qt * 64;

    float* Pf = (float*)smem + wave * 640;   // wave-private [16][40] f32, overlays K

    // ---- preload Q fragments (rows wave*16+fr), f32 -> hi/lo
    bf16x8 qh[4], ql[4];
    #pragma unroll
    for (int kt = 0; kt < 4; kt++) {
        const float* src = Q + (q0 + wave * 16 + fr) * D + h * 128 + kt * 32 + fq * 8;
        float4 f0 = ((const float4*)src)[0], f1 = ((const float4*)src)[1];
        float v[8] = {f0.x, f0.y, f0.z, f0.w, f1.x, f1.y, f1.z, f1.w};
        cvt8(v, qh[kt], ql[kt]);
    }

    f32x4v o[8] = {};
    float m_run[4], l_run[4];
    #pragma unroll
    for (int r = 0; r < 4; r++) { m_run[r] = -1e30f; l_run[r] = 0.f; }

    for (int j0 = s * SPAN; j0 < (s + 1) * SPAN; j0 += 32) {
        __syncthreads();   // A: prior P (K-region) and V reads complete
        // ---- stage K (32 x 128), 2 chunks/thread
        #pragma unroll
        for (int g = 0; g < 2; g++) {
            const int cid = g * 256 + tid;
            const int n = cid >> 4, k8 = cid & 15;
            const long gsrc = (long)(j0 + n) * D + h * 128 + k8 * 8;
            const int off = n * 128 + ((k8 ^ (n & 15)) << 3);
            *(bf16x8*)&Kh[off] = *(const bf16x8*)&Khi[gsrc];
            *(bf16x8*)&Kl[off] = *(const bf16x8*)&Klo[gsrc];
        }
        // ---- stage V (128 x 32, padded stride 40)
        #pragma unroll
        for (int g = 0; g < 2; g++) {
            const int cid = g * 256 + tid;
            const int d = cid >> 2, k8 = cid & 3;
            const long gsrc = (long)(h * 128 + d) * N + j0 + k8 * 8;
            const int off = d * VSTR + k8 * 8;
            *(bf16x8*)&Vh[off] = *(const bf16x8*)&Vthi[gsrc];
            *(bf16x8*)&Vl[off] = *(const bf16x8*)&Vtlo[gsrc];
        }
        __syncthreads();   // B: staging visible

        // ---- S = Q K^T : 16 rows x 32 cols per wave
        f32x4v sacc[2] = {};
        #pragma unroll
        for (int jb = 0; jb < 2; jb++) {
            bf16x8 kh[4], km[4];
            #pragma unroll
            for (int kt = 0; kt < 4; kt++) {
                const int col = jb * 16 + fr;
                const int k8 = kt * 4 + fq;
                const int off = col * 128 + ((k8 ^ (col & 15)) << 3);
                kh[kt] = *(const bf16x8*)&Kh[off];
                km[kt] = *(const bf16x8*)&Kl[off];
            }
            #pragma unroll
            for (int kt = 0; kt < 4; kt++) {
                sacc[jb] = __builtin_amdgcn_mfma_f32_16x16x32_bf16(ql[kt], kh[kt], sacc[jb], 0, 0, 0);
                sacc[jb] = __builtin_amdgcn_mfma_f32_16x16x32_bf16(qh[kt], km[kt], sacc[jb], 0, 0, 0);
                sacc[jb] = __builtin_amdgcn_mfma_f32_16x16x32_bf16(qh[kt], kh[kt], sacc[jb], 0, 0, 0);
            }
        }

        // ---- online softmax (log2 domain), within-wave
        float t[2][4], mloc[4];
        #pragma unroll
        for (int r = 0; r < 4; r++) {
            float a = sacc[0][r] * TS, b = sacc[1][r] * TS;
            t[0][r] = a; t[1][r] = b;
            mloc[r] = fmaxf(a, b);
        }
        #pragma unroll
        for (int bmask = 1; bmask <= 8; bmask <<= 1)
            #pragma unroll
            for (int r = 0; r < 4; r++)
                mloc[r] = fmaxf(mloc[r], __shfl_xor(mloc[r], bmask));
        float alpha_[4], rs[4];
        #pragma unroll
        for (int r = 0; r < 4; r++) {
            const float mn = fmaxf(m_run[r], mloc[r]);
            alpha_[r] = exp2f(m_run[r] - mn);
            m_run[r] = mn;
            rs[r] = 0.f;
        }
        __syncthreads();   // C: all waves' K-fragment reads complete (P overlays K)
        #pragma unroll
        for (int jb = 0; jb < 2; jb++)
            #pragma unroll
            for (int r = 0; r < 4; r++) {
                const float p = exp2f(t[jb][r] - m_run[r]);
                rs[r] += p;
                Pf[(fq * 4 + r) * PSTR + jb * 16 + fr] = p;
            }
        #pragma unroll
        for (int bmask = 1; bmask <= 8; bmask <<= 1)
            #pragma unroll
            for (int r = 0; r < 4; r++)
                rs[r] += __shfl_xor(rs[r], bmask);
        #pragma unroll
        for (int r = 0; r < 4; r++)
            l_run[r] = l_run[r] * alpha_[r] + rs[r];
        #pragma unroll
        for (int jbo = 0; jbo < 8; jbo++)
            #pragma unroll
            for (int r = 0; r < 4; r++)
                o[jbo][r] *= alpha_[r];

        // ---- PV: O[16 x 128] += P[16 x 32] V[32 x 128]  (P wave-private)
        bf16x8 ph, pl;
        {
            const float* base = &Pf[fr * PSTR + fq * 8];
            float4 f0 = ((const float4*)base)[0], f1 = ((const float4*)base)[1];
            float v[8] = {f0.x, f0.y, f0.z, f0.w, f1.x, f1.y, f1.z, f1.w};
            cvt8(v, ph, pl);
        }
        #pragma unroll
        for (int jbo = 0; jbo < 8; jbo++) {
            const int col = jbo * 16 + fr;
            const int off = col * VSTR + fq * 8;
            bf16x8 vh_ = *(const bf16x8*)&Vh[off];
            bf16x8 vl_ = *(const bf16x8*)&Vl[off];
            o[jbo] = __builtin_amdgcn_mfma_f32_16x16x32_bf16(pl, vh_, o[jbo], 0, 0, 0);
            o[jbo] = __builtin_amdgcn_mfma_f32_16x16x32_bf16(ph, vl_, o[jbo], 0, 0, 0);
            o[jbo] = __builtin_amdgcn_mfma_f32_16x16x32_bf16(ph, vh_, o[jbo], 0, 0, 0);
        }
    }

    // ---- store unnormalized partial O + (m, l)
    const long sidx = ((long)(h * 64 + qt)) * 4 + s;
    float* ob = Op + sidx * 8192;
    #pragma unroll
    for (int jbo = 0; jbo < 8; jbo++)
        #pragma unroll
        for (int r = 0; r < 4; r++) {
            const int lrow = wave * 16 + fq * 4 + r;
            ob[lrow * 128 + jbo * 16 + fr] = o[jbo][r];
        }
    if (fr == 0) {
        #pragma unroll
        for (int r = 0; r < 4; r++) {
            const int lrow = wave * 16 + fq * 4 + r;
            ml[sidx * 128 + lrow]      = m_run[r];
            ml[sidx * 128 + 64 + lrow] = l_run[r];
        }
    }
}

// ---------------------------------------------------------------- merge 4 KV-splits (exact)
__global__ void flash_merge(const float* __restrict__ Op, const float* __restrict__ ml,
                            float* __restrict__ ctx)
{
    const int idx = blockIdx.x;            // h*64 + qt
    const int h = idx >> 6, qt = idx & 63;
    const int tid = threadIdx.x;
    __shared__ float es[4][64], il[64];
    if (tid < 64) {
        float m[4], l[4];
        #pragma unroll
        for (int s = 0; s < 4; s++) {
            m[s] = ml[(long)(idx * 4 + s) * 128 + tid];
            l[s] = ml[(long)(idx * 4 + s) * 128 + 64 + tid];
        }
        float mx = fmaxf(fmaxf(m[0], m[1]), fmaxf(m[2], m[3]));
        float denom = 0.f;
        #pragma unroll
        for (int s = 0; s < 4; s++) {
            const float e = exp2f(m[s] - mx);
            es[s][tid] = e;
            denom += e * l[s];
        }
        il[tid] = 1.f / denom;
    }
    __syncthreads();
    const long b = ((long)idx * 4) * 8192;
    #pragma unroll
    for (int i = 0; i < 32; i++) {
        const int e = tid + i * 256;
        const int row = e >> 7, col = e & 127;
        float v = es[0][row] * Op[b + e] + es[1][row] * Op[b + 8192 + e]
                + es[2][row] * Op[b + 16384 + e] + es[3][row] * Op[b + 24576 + e];
        ctx[(long)(qt * 64 + row) * 512 + h * 128 + col] = v * il[row];
    }
}

// ---------------------------------------------------------------- residual + layernorm (f32, D=512)
__global__ void add_ln_f32(const float* __restrict__ a, const float* __restrict__ b,
                           const float* __restrict__ g, const float* __restrict__ be,
                           float* __restrict__ out)
{
    const long row = blockIdx.x;
    const int tid = threadIdx.x;
    const long base = row * 512L;
    float x0 = a[base + tid]       + b[base + tid];
    float x1 = a[base + tid + 256] + b[base + tid + 256];
    float s = block_reduce_sum256(x0 + x1);
    float mu = s * (1.f / 512.f);
    float d0 = x0 - mu, d1 = x1 - mu;
    float var = block_reduce_sum256(d0 * d0 + d1 * d1) * (1.f / 512.f);
    float invs = rsqrtf(var + 1e-6f);
    out[base + tid]       = d0 * invs * g[tid]       + be[tid];
    out[base + tid + 256] = d1 * invs * g[tid + 256] + be[tid + 256];
}

// ---------------------------------------------------------------- normalize emb rows (f32, E=512)
__global__ void normalize_emb(const float* __restrict__ emb, float* __restrict__ embn)
{
    const long row = blockIdx.x;
    const int tid = threadIdx.x;
    const long base = row * 512L;
    float a0 = emb[base + tid];
    float a1 = emb[base + tid + 256];
    float ss = block_reduce_sum256(a0 * a0 + a1 * a1);
    float sc = rsqrtf(fmaxf(ss, 1e-12f));
    embn[base + tid]       = a0 * sc;
    embn[base + tid + 256] = a1 * sc;
}

// ---------------------------------------------------------------- VQ: argmax -> one-hot in place + gather vq_feat
__global__ void vq_select_onehot(float* __restrict__ sims, const float* __restrict__ emb,
                                 float* __restrict__ vq_out)
{
    __shared__ float sv[256];
    __shared__ int   si[256];
    const long row = blockIdx.x;
    const int tid = threadIdx.x;
    float* s = sims + row * 1024L;
    float v0 = s[tid], v1 = s[tid + 256], v2 = s[tid + 512], v3 = s[tid + 768];
    float best = v0; int bi = tid;
    if (v1 > best) { best = v1; bi = tid + 256; }
    if (v2 > best) { best = v2; bi = tid + 512; }
    if (v3 > best) { best = v3; bi = tid + 768; }
    sv[tid] = best; si[tid] = bi; __syncthreads();
    #pragma unroll
    for (int st = 128; st > 0; st >>= 1) {
        if (tid < st) {
            if (sv[tid + st] > sv[tid] ||
                (sv[tid + st] == sv[tid] && si[tid + st] < si[tid])) {
                sv[tid] = sv[tid + st]; si[tid] = si[tid + st];
            }
        }
        __syncthreads();
    }
    const int idx = si[0];
    s[tid]       = (tid       == idx) ? 1.f : 0.f;
    s[tid + 256] = (tid + 256 == idx) ? 1.f : 0.f;
    s[tid + 512] = (tid + 512 == idx) ? 1.f : 0.f;
    s[tid + 768] = (tid + 768 == idx) ? 1.f : 0.f;
    const float* er = emb + (long)idx * 512;
    float* vr = vq_out + row * 512L;
    vr[tid]       = er[tid];
    vr[tid + 256] = er[tid + 256];
}

// ---------------------------------------------------------------- host side
struct EncW {
    const float *wq, *wk, *wv, *wo, *w1, *w2;      // natural [K][N]
    const float *bq, *bk, *bv, *bo, *b1, *b2;
    const float *g1, *be1, *g2, *be2;
};

static void run_encoder_g3(hipStream_t stream, const float* x, const EncW& w,
                           float* qb, bf16* khi, bf16* klo, bf16* vthi, bf16* vtlo,
                           float* ctx, float* Op, float* ml,
                           float* x1, float* hb, float* out)
{
    const int N = 4096, D = 512;
    // fused q/k/v projection
    qkv_gemm<<<dim3(12, 64), 256, 0, stream>>>(
        x, w.wq, w.wk, w.wv, w.bq, w.bk, w.bv, qb, khi, klo, vthi, vtlo);
    // fused attention: 1024 blocks (4 KV-splits), exact merge -> ctx
    flash_attn<<<dim3(64, 4, 4), 256, 0, stream>>>(qb, khi, klo, vthi, vtlo, Op, ml);
    flash_merge<<<256, 256, 0, stream>>>(Op, ml, ctx);
    // wo projection, LN1, FFN, LN2
    gemm3<64, false, false, true, false><<<dim3(4, 64), 256, 0, stream>>>(
        ctx, w.wo, w.bo, qb, nullptr, nullptr, D, D, D, D, 1.f);
    add_ln_f32<<<N, 256, 0, stream>>>(x, qb, w.g1, w.be1, x1);
    gemm3<64, true, false, true, false><<<dim3(4, 64), 256, 0, stream>>>(
        x1, w.w1, w.b1, hb, nullptr, nullptr, D, D, D, D, 1.f);
    gemm3<64, false, false, true, false><<<dim3(4, 64), 256, 0, stream>>>(
        hb, w.w2, w.b2, qb, nullptr, nullptr, D, D, D, D, 1.f);
    add_ln_f32<<<N, 256, 0, stream>>>(x1, qb, w.g2, w.be2, out);
}

extern "C" void kernel_launch(void* const* d_in, const int* in_sizes, int n_in,
                              void* d_out, int out_size, void* d_ws, size_t ws_size,
                              hipStream_t stream)
{
    const int N = 4096, D = 512, E = 512, F = 4096, KCB = 1024;
    (void)in_sizes; (void)n_in; (void)out_size; (void)d_ws; (void)ws_size;

    const float* x_in  = (const float*)d_in[0];
    const float* fc1_w = (const float*)d_in[33];
    const float* fc1_b = (const float*)d_in[34];
    const float* fc2_w = (const float*)d_in[35];
    const float* fc2_b = (const float*)d_in[36];
    const float* emb   = (const float*)d_in[37];

    // ---- output regions (f32); context_ind = one-hot [N, K]
    float* out0 = (float*)d_out;                  // encoded [N,E]       8 MB
    float* out1 = out0 + (size_t)N * E;           // vq_feat [N,E]       8 MB
    float* out2 = out1 + (size_t)N * E;           // one_hot [N,K]      16 MB
    float* out3 = out2 + (size_t)N * KCB;         // decoded [N,F]      64 MB
    float* out4 = out3 + (size_t)N * F;           // emb copy [K,E]      2 MB

    // ---- arena inside out3 (64 MB); dead before the fc2 writes reach it
    char* arena = (char*)out3;
    const size_t MB = 1024 * 1024;
    float* qb     = (float*)(arena + 0 * MB);     // [0,8)
    bf16*  khi    = (bf16*) (arena + 8 * MB);     // [8,12)
    bf16*  klo    = (bf16*) (arena + 12 * MB);    // [12,16)
    bf16*  vthi   = (bf16*) (arena + 16 * MB);    // [16,20)
    bf16*  vtlo   = (bf16*) (arena + 20 * MB);    // [20,24)
    float* ctx    = (float*)(arena + 24 * MB);    // [24,32)
    float* Op     = (float*)(arena + 32 * MB);    // [32,64): 1024 x 8192 f32 partials
    float* decout = (float*)(arena + 56 * MB);    // [56,64): written after Op dead
    float* x1     = (float*)(arena + 16 * MB);    // reuse KV region after attention
    float* hb     = (float*)(arena + 8 * MB);
    float* ml     = (float*)out4;                 // 512 KB in emb-copy region (dead until end)
    float* embn   = out1;                         // dead until vq_select
    float* stage  = (float*)out4;                 // fc2 staging (after ml dead)

    EncW ew = { (const float*)d_in[1],  (const float*)d_in[2],  (const float*)d_in[3],
                (const float*)d_in[4],  (const float*)d_in[5],  (const float*)d_in[6],
                (const float*)d_in[7],  (const float*)d_in[8],  (const float*)d_in[9],
                (const float*)d_in[10], (const float*)d_in[11], (const float*)d_in[12],
                (const float*)d_in[13], (const float*)d_in[14], (const float*)d_in[15],
                (const float*)d_in[16] };
    EncW dw = { (const float*)d_in[17], (const float*)d_in[18], (const float*)d_in[19],
                (const float*)d_in[20], (const float*)d_in[21], (const float*)d_in[22],
                (const float*)d_in[23], (const float*)d_in[24], (const float*)d_in[25],
                (const float*)d_in[26], (const float*)d_in[27], (const float*)d_in[28],
                (const float*)d_in[29], (const float*)d_in[30], (const float*)d_in[31],
                (const float*)d_in[32] };

    // ---- phase E: encoder -> ctx
    normalize_emb<<<KCB, 256, 0, stream>>>(emb, embn);
    run_encoder_g3(stream, x_in, ew, qb, khi, klo, vthi, vtlo, ctx, Op, ml, x1, hb, ctx);

    // ---- phase F: fc1 -> encoded (out0)
    gemm3<64, false, false, true, false><<<dim3(4, 64), 256, 0, stream>>>(
        ctx, fc1_w, fc1_b, out0, nullptr, nullptr, D, D, E, E, 1.f);

    // ---- phase V: sims = encoded @ embn^T into out2; argmax -> one-hot + gather
    gemm3<128, false, false, false, false><<<dim3(8, 32), 256, 0, stream>>>(
        out0, embn, nullptr, out2, nullptr, nullptr, E, E, E, KCB, 1.f);
    vq_select_onehot<<<N, 256, 0, stream>>>(out2, emb, out1);

    // ---- phase D: decoder -> decout [56,64)
    run_encoder_g3(stream, out1, dw, qb, khi, klo, vthi, vtlo, ctx, Op, ml, x1, hb, decout);

    // ---- phase G: fc2 + relu (B natural). Rows [0,3584) write [0,56M) (disjoint
    // from decout); rows [3584,4096) read a staged copy since their writes cover decout.
    hipMemcpyAsync(stage, decout + (size_t)3584 * D, (size_t)512 * D * sizeof(float),
                   hipMemcpyDeviceToDevice, stream);
    gemm3<128, true, false, true, false><<<dim3(F / 128, 3584 / 128), 256, 0, stream>>>(
        decout, fc2_w, fc2_b, out3, nullptr, nullptr, D, D, F, F, 1.f);
    gemm3<128, true, false, true, false><<<dim3(F / 128, 512 / 128), 256, 0, stream>>>(
        stage, fc2_w, fc2_b, out3 + (size_t)3584 * F, nullptr, nullptr, D, D, F, F, 1.f);

    // ---- emb copy last (out4 was ml/staging)
    hipMemcpyAsync(out4, emb, (size_t)KCB * E * sizeof(float), hipMemcpyDeviceToDevice, stream);
}

// Round 10
// 968.423 us; speedup vs baseline: 1.0659x; 1.0659x over previous
//
#include <hip/hip_runtime.h>
#include <hip/hip_bf16.h>
#include <stdint.h>

typedef __bf16 bf16;
typedef __bf16 bf16x8 __attribute__((ext_vector_type(8)));
typedef float  f32x4v __attribute__((ext_vector_type(4)));

__device__ __forceinline__ void cvt8(const float* v, bf16x8& hh, bf16x8& ll) {
    #pragma unroll
    for (int j = 0; j < 8; j++) {
        bf16 b = (bf16)v[j]; hh[j] = b; ll[j] = (bf16)(v[j] - (float)b);
    }
}

// ---------------------------------------------------------------- reductions
__device__ __forceinline__ float block_reduce_sum256(float v) {
    __shared__ float red[256];
    int tid = threadIdx.x;
    red[tid] = v; __syncthreads();
    #pragma unroll
    for (int s = 128; s > 0; s >>= 1) {
        if (tid < s) red[tid] += red[tid + s];
        __syncthreads();
    }
    float r = red[0]; __syncthreads();
    return r;
}

// ---------------------------------------------------------------- bf16x3 split-MFMA GEMM
template<int BMT, bool RELU, bool TRANS, bool BNAT, bool HILO>
__global__ __launch_bounds__(256, 2)
void gemm3(const float* __restrict__ A, const float* __restrict__ B,
           const float* __restrict__ bias, float* __restrict__ C,
           bf16* __restrict__ Chi, bf16* __restrict__ Clo,
           int K, int lda, int ldb, int ldc, float alpha)
{
    constexpr int BN = 128, TK = 32;
    constexpr int RM = BMT / 32;
    __shared__ __align__(16) bf16 Ah[BMT * TK];
    __shared__ __align__(16) bf16 Al[BMT * TK];
    __shared__ __align__(16) bf16 Bh[BN * TK];
    __shared__ __align__(16) bf16 Bl[BN * TK];

    const int tid  = threadIdx.x;
    const int wave = tid >> 6, lane = tid & 63;
    const int wr = wave >> 1, wc = wave & 1;
    const long bm = (long)blockIdx.y * BMT;
    const long bn = (long)blockIdx.x * BN;
    const int fr = lane & 15, fq = lane >> 4;

    f32x4v acc[RM][4] = {};

    for (int k0 = 0; k0 < K; k0 += TK) {
        #pragma unroll
        for (int it = 0; it < BMT / 64; it++) {
            const int c = it * 256 + tid;
            const int r = c >> 2, k8 = c & 3;
            const float* src = A + (bm + r) * (long)lda + k0 + k8 * 8;
            float4 f0 = ((const float4*)src)[0], f1 = ((const float4*)src)[1];
            float v[8] = {f0.x, f0.y, f0.z, f0.w, f1.x, f1.y, f1.z, f1.w};
            bf16x8 hh, ll; cvt8(v, hh, ll);
            *(bf16x8*)&Ah[r * TK + k8 * 8] = hh;
            *(bf16x8*)&Al[r * TK + k8 * 8] = ll;
        }
        if (BNAT) {
            const int col = tid & 127, bkh = (tid >> 7) * 16;
            const float* src = B + (long)(k0 + bkh) * ldb + bn + col;
            float v[16];
            #pragma unroll
            for (int kk = 0; kk < 16; kk++) v[kk] = src[(long)kk * ldb];
            bf16x8 h0, l0, h1, l1; cvt8(v, h0, l0); cvt8(v + 8, h1, l1);
            bf16* hd = &Bh[col * TK + bkh];
            bf16* ld_ = &Bl[col * TK + bkh];
            ((bf16x8*)hd)[0] = h0; ((bf16x8*)hd)[1] = h1;
            ((bf16x8*)ld_)[0] = l0; ((bf16x8*)ld_)[1] = l1;
        } else {
            #pragma unroll
            for (int it = 0; it < 2; it++) {
                const int c = it * 256 + tid;
                const int r = c >> 2, k8 = c & 3;
                const float* src = B + (bn + r) * (long)ldb + k0 + k8 * 8;
                float4 f0 = ((const float4*)src)[0], f1 = ((const float4*)src)[1];
                float v[8] = {f0.x, f0.y, f0.z, f0.w, f1.x, f1.y, f1.z, f1.w};
                bf16x8 hh, ll; cvt8(v, hh, ll);
                *(bf16x8*)&Bh[r * TK + k8 * 8] = hh;
                *(bf16x8*)&Bl[r * TK + k8 * 8] = ll;
            }
        }
        __syncthreads();

        bf16x8 ah[RM], am[RM], bh[4], bm_[4];
        #pragma unroll
        for (int i = 0; i < RM; i++) {
            const int r = (wr * (BMT / 2) + i * 16 + fr) * TK + fq * 8;
            ah[i] = *(const bf16x8*)&Ah[r];
            am[i] = *(const bf16x8*)&Al[r];
        }
        #pragma unroll
        for (int j = 0; j < 4; j++) {
            const int r = (wc * 64 + j * 16 + fr) * TK + fq * 8;
            bh[j] = *(const bf16x8*)&Bh[r];
            bm_[j] = *(const bf16x8*)&Bl[r];
        }
        #pragma unroll
        for (int i = 0; i < RM; i++)
            #pragma unroll
            for (int j = 0; j < 4; j++) {
                acc[i][j] = __builtin_amdgcn_mfma_f32_16x16x32_bf16(am[i], bh[j], acc[i][j], 0, 0, 0);
                acc[i][j] = __builtin_amdgcn_mfma_f32_16x16x32_bf16(ah[i], bm_[j], acc[i][j], 0, 0, 0);
                acc[i][j] = __builtin_amdgcn_mfma_f32_16x16x32_bf16(ah[i], bh[j], acc[i][j], 0, 0, 0);
            }
        __syncthreads();
    }

    #pragma unroll
    for (int i = 0; i < RM; i++) {
        #pragma unroll
        for (int j = 0; j < 4; j++) {
            const long col = bn + wc * 64 + j * 16 + fr;
            const float bv = bias ? bias[col] : 0.f;
            #pragma unroll
            for (int r = 0; r < 4; r++) {
                const long row = bm + wr * (BMT / 2) + i * 16 + fq * 4 + r;
                float v = acc[i][j][r] * alpha + bv;
                if (RELU) v = fmaxf(v, 0.f);
                const long idx = TRANS ? (col * (long)ldc + row) : (row * (long)ldc + col);
                if (HILO) {
                    bf16 hh = (bf16)v;
                    Chi[idx] = hh;
                    Clo[idx] = (bf16)(v - (float)hh);
                } else {
                    C[idx] = v;
                }
            }
        }
    }
}

// ---------------------------------------------------------------- fused QKV projection
__global__ __launch_bounds__(256, 2)
void qkv_gemm(const float* __restrict__ X,
              const float* __restrict__ Wq, const float* __restrict__ Wk, const float* __restrict__ Wv,
              const float* __restrict__ Bq, const float* __restrict__ Bk, const float* __restrict__ Bv,
              float* __restrict__ Qo, bf16* __restrict__ Khi, bf16* __restrict__ Klo,
              bf16* __restrict__ Vthi, bf16* __restrict__ Vtlo)
{
    constexpr int TK = 32, D = 512, N = 4096;
    __shared__ __align__(16) bf16 Ah[64 * TK];
    __shared__ __align__(16) bf16 Al[64 * TK];
    __shared__ __align__(16) bf16 Bh[128 * TK];
    __shared__ __align__(16) bf16 Bl[128 * TK];

    const int tid  = threadIdx.x;
    const int wave = tid >> 6, lane = tid & 63;
    const int wr = wave >> 1, wc = wave & 1;
    const int sel = blockIdx.x >> 2, wcol0 = (blockIdx.x & 3) * 128;
    const long bm = (long)blockIdx.y * 64;
    const int fr = lane & 15, fq = lane >> 4;

    const float* W  = sel == 0 ? Wq : (sel == 1 ? Wk : Wv);
    const float* Bb = sel == 0 ? Bq : (sel == 1 ? Bk : Bv);

    f32x4v acc[2][4] = {};

    for (int k0 = 0; k0 < D; k0 += TK) {
        {
            const int r = tid >> 2, k8 = tid & 3;
            const float* src = X + (bm + r) * (long)D + k0 + k8 * 8;
            float4 f0 = ((const float4*)src)[0], f1 = ((const float4*)src)[1];
            float v[8] = {f0.x, f0.y, f0.z, f0.w, f1.x, f1.y, f1.z, f1.w};
            bf16x8 hh, ll; cvt8(v, hh, ll);
            *(bf16x8*)&Ah[r * TK + k8 * 8] = hh;
            *(bf16x8*)&Al[r * TK + k8 * 8] = ll;
        }
        {
            const int col = tid & 127, bkh = (tid >> 7) * 16;
            const float* src = W + (long)(k0 + bkh) * D + wcol0 + col;
            float v[16];
            #pragma unroll
            for (int kk = 0; kk < 16; kk++) v[kk] = src[(long)kk * D];
            bf16x8 h0, l0, h1, l1; cvt8(v, h0, l0); cvt8(v + 8, h1, l1);
            bf16* hd = &Bh[col * TK + bkh];
            bf16* ld_ = &Bl[col * TK + bkh];
            ((bf16x8*)hd)[0] = h0; ((bf16x8*)hd)[1] = h1;
            ((bf16x8*)ld_)[0] = l0; ((bf16x8*)ld_)[1] = l1;
        }
        __syncthreads();

        bf16x8 ah[2], am[2], bh[4], bm_[4];
        #pragma unroll
        for (int i = 0; i < 2; i++) {
            const int r = (wr * 32 + i * 16 + fr) * TK + fq * 8;
            ah[i] = *(const bf16x8*)&Ah[r];
            am[i] = *(const bf16x8*)&Al[r];
        }
        #pragma unroll
        for (int j = 0; j < 4; j++) {
            const int r = (wc * 64 + j * 16 + fr) * TK + fq * 8;
            bh[j] = *(const bf16x8*)&Bh[r];
            bm_[j] = *(const bf16x8*)&Bl[r];
        }
        #pragma unroll
        for (int i = 0; i < 2; i++)
            #pragma unroll
            for (int j = 0; j < 4; j++) {
                acc[i][j] = __builtin_amdgcn_mfma_f32_16x16x32_bf16(am[i], bh[j], acc[i][j], 0, 0, 0);
                acc[i][j] = __builtin_amdgcn_mfma_f32_16x16x32_bf16(ah[i], bm_[j], acc[i][j], 0, 0, 0);
                acc[i][j] = __builtin_amdgcn_mfma_f32_16x16x32_bf16(ah[i], bh[j], acc[i][j], 0, 0, 0);
            }
        __syncthreads();
    }

    #pragma unroll
    for (int i = 0; i < 2; i++) {
        #pragma unroll
        for (int j = 0; j < 4; j++) {
            const int col = wc * 64 + j * 16 + fr;
            const float bv = Bb[wcol0 + col];
            #pragma unroll
            for (int r = 0; r < 4; r++) {
                const long row = bm + wr * 32 + i * 16 + fq * 4 + r;
                const float v = acc[i][j][r] + bv;
                if (sel == 0) {
                    Qo[row * D + wcol0 + col] = v;
                } else {
                    const bf16 hh = (bf16)v;
                    const bf16 ll = (bf16)(v - (float)hh);
                    const long idx = (sel == 1) ? (row * (long)D + wcol0 + col)
                                                : ((long)(wcol0 + col) * N + row);
                    if (sel == 1) { Khi[idx] = hh; Klo[idx] = ll; }
                    else          { Vthi[idx] = hh; Vtlo[idx] = ll; }
                }
            }
        }
    }
}

// ---------------------------------------------------------------- fused flash attention v3
// BQ=128 Q rows/block (wave owns 32 rows), KV tile 64, KV-split 4.
// Grid (32, 4, 4) = 512 blocks, LDS 64 KB -> 2 blocks/CU.
// K/V tiles: round-8 XOR-swizzled layouts (measured ~1M conflicts).
// P: wave-private [16][68] f32 buffer overlaid on K region, reused for both
// row-groups (in-wave DS ordering). P+V fragments hoisted -> V reads amortized.
__global__ __launch_bounds__(256, 2)
void flash_attn(const float* __restrict__ Q,
                const bf16* __restrict__ Khi, const bf16* __restrict__ Klo,
                const bf16* __restrict__ Vthi, const bf16* __restrict__ Vtlo,
                float* __restrict__ Op, float* __restrict__ ml)
{
    constexpr int N = 4096, D = 512, SPAN = 1024;
    constexpr float TS = 0.12751791f;   // (1/sqrt(128)) * log2(e)
    constexpr int PSTR = 68;

    __shared__ __align__(16) bf16 smem[32768];   // 64 KB
    bf16* Kh = smem;                  // [64][128] xor-swizzled (16 KB)
    bf16* Kl = smem + 8192;
    bf16* Vh = smem + 16384;          // [128][64] xor-swizzled
    bf16* Vl = smem + 24576;

    const int tid = threadIdx.x;
    const int wave = tid >> 6, lane = tid & 63;
    const int fr = lane & 15, fq = lane >> 4;
    const int qt = blockIdx.x, h = blockIdx.y, s = blockIdx.z;
    const long q0 = (long)qt * 128;

    float* Pf = (float*)smem + wave * (16 * PSTR);   // 4.25 KB/wave, 17 KB total over K

    // ---- preload Q fragments (2 row-groups x 32 rows/wave), f32 -> hi/lo
    bf16x8 qh[2][4], ql[2][4];
    #pragma unroll
    for (int rg = 0; rg < 2; rg++)
        #pragma unroll
        for (int kt = 0; kt < 4; kt++) {
            const float* src = Q + (q0 + wave * 32 + rg * 16 + fr) * D + h * 128 + kt * 32 + fq * 8;
            float4 f0 = ((const float4*)src)[0], f1 = ((const float4*)src)[1];
            float v[8] = {f0.x, f0.y, f0.z, f0.w, f1.x, f1.y, f1.z, f1.w};
            cvt8(v, qh[rg][kt], ql[rg][kt]);
        }

    f32x4v o[2][8] = {};
    float m_run[2][4], l_run[2][4];
    #pragma unroll
    for (int rg = 0; rg < 2; rg++)
        #pragma unroll
        for (int r = 0; r < 4; r++) { m_run[rg][r] = -1e30f; l_run[rg][r] = 0.f; }

    for (int j0 = s * SPAN; j0 < (s + 1) * SPAN; j0 += 64) {
        __syncthreads();   // A: all waves' P/V reads of previous iter complete
        // ---- stage K (64 x 128), 4 chunks/thread
        #pragma unroll
        for (int g = 0; g < 4; g++) {
            const int cid = g * 256 + tid;
            const int n = cid >> 4, k8 = cid & 15;
            const long gsrc = (long)(j0 + n) * D + h * 128 + k8 * 8;
            const int off = n * 128 + ((k8 ^ (n & 15)) << 3);
            *(bf16x8*)&Kh[off] = *(const bf16x8*)&Khi[gsrc];
            *(bf16x8*)&Kl[off] = *(const bf16x8*)&Klo[gsrc];
        }
        // ---- stage V (128 x 64)
        #pragma unroll
        for (int g = 0; g < 4; g++) {
            const int cid = g * 256 + tid;
            const int d = cid >> 3, k8 = cid & 7;
            const long gsrc = (long)(h * 128 + d) * N + j0 + k8 * 8;
            const int off = d * 64 + ((k8 ^ (d & 7)) << 3);
            *(bf16x8*)&Vh[off] = *(const bf16x8*)&Vthi[gsrc];
            *(bf16x8*)&Vl[off] = *(const bf16x8*)&Vtlo[gsrc];
        }
        __syncthreads();   // B: staging visible

        // ---- S = Q K^T : 32 rows x 64 cols per wave; K frags amortized over 2 rg
        f32x4v sacc[2][4] = {};
        #pragma unroll
        for (int jb = 0; jb < 4; jb++) {
            bf16x8 kh[4], km[4];
            #pragma unroll
            for (int kt = 0; kt < 4; kt++) {
                const int col = jb * 16 + fr;
                const int k8 = kt * 4 + fq;
                const int off = col * 128 + ((k8 ^ (col & 15)) << 3);
                kh[kt] = *(const bf16x8*)&Kh[off];
                km[kt] = *(const bf16x8*)&Kl[off];
            }
            #pragma unroll
            for (int kt = 0; kt < 4; kt++)
                #pragma unroll
                for (int rg = 0; rg < 2; rg++) {
                    sacc[rg][jb] = __builtin_amdgcn_mfma_f32_16x16x32_bf16(ql[rg][kt], kh[kt], sacc[rg][jb], 0, 0, 0);
                    sacc[rg][jb] = __builtin_amdgcn_mfma_f32_16x16x32_bf16(qh[rg][kt], km[kt], sacc[rg][jb], 0, 0, 0);
                    sacc[rg][jb] = __builtin_amdgcn_mfma_f32_16x16x32_bf16(qh[rg][kt], kh[kt], sacc[rg][jb], 0, 0, 0);
                }
        }

        // ---- online softmax (log2 domain), within-wave
        float t[2][4][4], alpha_[2][4], rs[2][4];
        #pragma unroll
        for (int rg = 0; rg < 2; rg++) {
            float mloc[4];
            #pragma unroll
            for (int r = 0; r < 4; r++) {
                float a = sacc[rg][0][r] * TS, b = sacc[rg][1][r] * TS;
                float c = sacc[rg][2][r] * TS, d2 = sacc[rg][3][r] * TS;
                t[rg][0][r] = a; t[rg][1][r] = b; t[rg][2][r] = c; t[rg][3][r] = d2;
                mloc[r] = fmaxf(fmaxf(a, b), fmaxf(c, d2));
            }
            #pragma unroll
            for (int bmask = 1; bmask <= 8; bmask <<= 1)
                #pragma unroll
                for (int r = 0; r < 4; r++)
                    mloc[r] = fmaxf(mloc[r], __shfl_xor(mloc[r], bmask));
            #pragma unroll
            for (int r = 0; r < 4; r++) {
                const float mn = fmaxf(m_run[rg][r], mloc[r]);
                alpha_[rg][r] = exp2f(m_run[rg][r] - mn);
                m_run[rg][r] = mn;
                rs[rg][r] = 0.f;
            }
        }
        __syncthreads();   // C: all waves' K-fragment reads complete (P overlays K)

        // ---- P: write rows + read fragments per rg (buffer reused; in-wave order)
        bf16x8 ph[2][2], pl[2][2];
        #pragma unroll
        for (int rg = 0; rg < 2; rg++) {
            #pragma unroll
            for (int jb = 0; jb < 4; jb++)
                #pragma unroll
                for (int r = 0; r < 4; r++) {
                    const float p = exp2f(t[rg][jb][r] - m_run[rg][r]);
                    rs[rg][r] += p;
                    Pf[(fq * 4 + r) * PSTR + jb * 16 + fr] = p;
                }
            #pragma unroll
            for (int bmask = 1; bmask <= 8; bmask <<= 1)
                #pragma unroll
                for (int r = 0; r < 4; r++)
                    rs[rg][r] += __shfl_xor(rs[rg][r], bmask);
            #pragma unroll
            for (int r = 0; r < 4; r++)
                l_run[rg][r] = l_run[rg][r] * alpha_[rg][r] + rs[rg][r];
            #pragma unroll
            for (int kt = 0; kt < 2; kt++) {
                const float* base = &Pf[fr * PSTR + kt * 32 + fq * 8];
                float4 f0 = ((const float4*)base)[0], f1 = ((const float4*)base)[1];
                float v[8] = {f0.x, f0.y, f0.z, f0.w, f1.x, f1.y, f1.z, f1.w};
                cvt8(v, ph[rg][kt], pl[rg][kt]);
            }
        }
        // ---- rescale O
        #pragma unroll
        for (int rg = 0; rg < 2; rg++)
            #pragma unroll
            for (int jbo = 0; jbo < 8; jbo++)
                #pragma unroll
                for (int r = 0; r < 4; r++)
                    o[rg][jbo][r] *= alpha_[rg][r];

        // ---- PV: V frags read once, used by both rg
        #pragma unroll
        for (int jbo = 0; jbo < 8; jbo++) {
            bf16x8 vh_[2], vl_[2];
            #pragma unroll
            for (int kt = 0; kt < 2; kt++) {
                const int col = jbo * 16 + fr;
                const int k8 = kt * 4 + fq;
                const int off = col * 64 + ((k8 ^ (col & 7)) << 3);
                vh_[kt] = *(const bf16x8*)&Vh[off];
                vl_[kt] = *(const bf16x8*)&Vl[off];
            }
            #pragma unroll
            for (int rg = 0; rg < 2; rg++)
                #pragma unroll
                for (int kt = 0; kt < 2; kt++) {
                    o[rg][jbo] = __builtin_amdgcn_mfma_f32_16x16x32_bf16(pl[rg][kt], vh_[kt], o[rg][jbo], 0, 0, 0);
                    o[rg][jbo] = __builtin_amdgcn_mfma_f32_16x16x32_bf16(ph[rg][kt], vl_[kt], o[rg][jbo], 0, 0, 0);
                    o[rg][jbo] = __builtin_amdgcn_mfma_f32_16x16x32_bf16(ph[rg][kt], vh_[kt], o[rg][jbo], 0, 0, 0);
                }
        }
    }

    // ---- store unnormalized partial O + (m, l)
    const long sidx = (long)((h * 32 + qt) * 4 + s);
    float* ob = Op + sidx * 16384;
    #pragma unroll
    for (int rg = 0; rg < 2; rg++)
        #pragma unroll
        for (int jbo = 0; jbo < 8; jbo++)
            #pragma unroll
            for (int r = 0; r < 4; r++) {
                const int lrow = wave * 32 + rg * 16 + fq * 4 + r;
                ob[lrow * 128 + jbo * 16 + fr] = o[rg][jbo][r];
            }
    if (fr == 0) {
        #pragma unroll
        for (int rg = 0; rg < 2; rg++)
            #pragma unroll
            for (int r = 0; r < 4; r++) {
                const int lrow = wave * 32 + rg * 16 + fq * 4 + r;
                ml[sidx * 256 + lrow]       = m_run[rg][r];
                ml[sidx * 256 + 128 + lrow] = l_run[rg][r];
            }
    }
}

// ---------------------------------------------------------------- merge 4 KV-splits (exact), 128-row tiles
__global__ void flash_merge(const float* __restrict__ Op, const float* __restrict__ ml,
                            float* __restrict__ ctx)
{
    const int idx = blockIdx.x;            // h*32 + qt, 128 blocks
    const int h = idx >> 5, qt = idx & 31;
    const int tid = threadIdx.x;
    __shared__ float es[4][128], il[128];
    if (tid < 128) {
        float m[4], l[4];
        #pragma unroll
        for (int s = 0; s < 4; s++) {
            m[s] = ml[(long)(idx * 4 + s) * 256 + tid];
            l[s] = ml[(long)(idx * 4 + s) * 256 + 128 + tid];
        }
        float mx = fmaxf(fmaxf(m[0], m[1]), fmaxf(m[2], m[3]));
        float denom = 0.f;
        #pragma unroll
        for (int s = 0; s < 4; s++) {
            const float e = exp2f(m[s] - mx);
            es[s][tid] = e;
            denom += e * l[s];
        }
        il[tid] = 1.f / denom;
    }
    __syncthreads();
    const long b = (long)idx * 4 * 16384;
    #pragma unroll
    for (int i = 0; i < 64; i++) {
        const int e = tid + i * 256;
        const int row = e >> 7, col = e & 127;
        float v = es[0][row] * Op[b + e] + es[1][row] * Op[b + 16384 + e]
                + es[2][row] * Op[b + 32768 + e] + es[3][row] * Op[b + 49152 + e];
        ctx[(long)(qt * 128 + row) * 512 + h * 128 + col] = v * il[row];
    }
}

// ---------------------------------------------------------------- residual + layernorm (f32, D=512)
__global__ void add_ln_f32(const float* __restrict__ a, const float* __restrict__ b,
                           const float* __restrict__ g, const float* __restrict__ be,
                           float* __restrict__ out)
{
    const long row = blockIdx.x;
    const int tid = threadIdx.x;
    const long base = row * 512L;
    float x0 = a[base + tid]       + b[base + tid];
    float x1 = a[base + tid + 256] + b[base + tid + 256];
    float s = block_reduce_sum256(x0 + x1);
    float mu = s * (1.f / 512.f);
    float d0 = x0 - mu, d1 = x1 - mu;
    float var = block_reduce_sum256(d0 * d0 + d1 * d1) * (1.f / 512.f);
    float invs = rsqrtf(var + 1e-6f);
    out[base + tid]       = d0 * invs * g[tid]       + be[tid];
    out[base + tid + 256] = d1 * invs * g[tid + 256] + be[tid + 256];
}

// ---------------------------------------------------------------- normalize emb rows (f32, E=512)
__global__ void normalize_emb(const float* __restrict__ emb, float* __restrict__ embn)
{
    const long row = blockIdx.x;
    const int tid = threadIdx.x;
    const long base = row * 512L;
    float a0 = emb[base + tid];
    float a1 = emb[base + tid + 256];
    float ss = block_reduce_sum256(a0 * a0 + a1 * a1);
    float sc = rsqrtf(fmaxf(ss, 1e-12f));
    embn[base + tid]       = a0 * sc;
    embn[base + tid + 256] = a1 * sc;
}

// ---------------------------------------------------------------- VQ: argmax -> one-hot in place + gather vq_feat
__global__ void vq_select_onehot(float* __restrict__ sims, const float* __restrict__ emb,
                                 float* __restrict__ vq_out)
{
    __shared__ float sv[256];
    __shared__ int   si[256];
    const long row = blockIdx.x;
    const int tid = threadIdx.x;
    float* s = sims + row * 1024L;
    float v0 = s[tid], v1 = s[tid + 256], v2 = s[tid + 512], v3 = s[tid + 768];
    float best = v0; int bi = tid;
    if (v1 > best) { best = v1; bi = tid + 256; }
    if (v2 > best) { best = v2; bi = tid + 512; }
    if (v3 > best) { best = v3; bi = tid + 768; }
    sv[tid] = best; si[tid] = bi; __syncthreads();
    #pragma unroll
    for (int st = 128; st > 0; st >>= 1) {
        if (tid < st) {
            if (sv[tid + st] > sv[tid] ||
                (sv[tid + st] == sv[tid] && si[tid + st] < si[tid])) {
                sv[tid] = sv[tid + st]; si[tid] = si[tid + st];
            }
        }
        __syncthreads();
    }
    const int idx = si[0];
    s[tid]       = (tid       == idx) ? 1.f : 0.f;
    s[tid + 256] = (tid + 256 == idx) ? 1.f : 0.f;
    s[tid + 512] = (tid + 512 == idx) ? 1.f : 0.f;
    s[tid + 768] = (tid + 768 == idx) ? 1.f : 0.f;
    const float* er = emb + (long)idx * 512;
    float* vr = vq_out + row * 512L;
    vr[tid]       = er[tid];
    vr[tid + 256] = er[tid + 256];
}

// ---------------------------------------------------------------- host side
struct EncW {
    const float *wq, *wk, *wv, *wo, *w1, *w2;      // natural [K][N]
    const float *bq, *bk, *bv, *bo, *b1, *b2;
    const float *g1, *be1, *g2, *be2;
};

static void run_encoder_g3(hipStream_t stream, const float* x, const EncW& w,
                           float* qb, bf16* khi, bf16* klo, bf16* vthi, bf16* vtlo,
                           float* ctx, float* Op, float* ml,
                           float* x1, float* hb, float* out)
{
    const int N = 4096, D = 512;
    // fused q/k/v projection
    qkv_gemm<<<dim3(12, 64), 256, 0, stream>>>(
        x, w.wq, w.wk, w.wv, w.bq, w.bk, w.bv, qb, khi, klo, vthi, vtlo);
    // fused attention: 512 blocks (BQ=128, 4 KV-splits), exact merge -> ctx
    flash_attn<<<dim3(32, 4, 4), 256, 0, stream>>>(qb, khi, klo, vthi, vtlo, Op, ml);
    flash_merge<<<128, 256, 0, stream>>>(Op, ml, ctx);
    // wo projection, LN1, FFN, LN2
    gemm3<64, false, false, true, false><<<dim3(4, 64), 256, 0, stream>>>(
        ctx, w.wo, w.bo, qb, nullptr, nullptr, D, D, D, D, 1.f);
    add_ln_f32<<<N, 256, 0, stream>>>(x, qb, w.g1, w.be1, x1);
    gemm3<64, true, false, true, false><<<dim3(4, 64), 256, 0, stream>>>(
        x1, w.w1, w.b1, hb, nullptr, nullptr, D, D, D, D, 1.f);
    gemm3<64, false, false, true, false><<<dim3(4, 64), 256, 0, stream>>>(
        hb, w.w2, w.b2, qb, nullptr, nullptr, D, D, D, D, 1.f);
    add_ln_f32<<<N, 256, 0, stream>>>(x1, qb, w.g2, w.be2, out);
}

extern "C" void kernel_launch(void* const* d_in, const int* in_sizes, int n_in,
                              void* d_out, int out_size, void* d_ws, size_t ws_size,
                              hipStream_t stream)
{
    const int N = 4096, D = 512, E = 512, F = 4096, KCB = 1024;
    (void)in_sizes; (void)n_in; (void)out_size; (void)d_ws; (void)ws_size;

    const float* x_in  = (const float*)d_in[0];
    const float* fc1_w = (const float*)d_in[33];
    const float* fc1_b = (const float*)d_in[34];
    const float* fc2_w = (const float*)d_in[35];
    const float* fc2_b = (const float*)d_in[36];
    const float* emb   = (const float*)d_in[37];

    // ---- output regions (f32); context_ind = one-hot [N, K]
    float* out0 = (float*)d_out;                  // encoded [N,E]       8 MB
    float* out1 = out0 + (size_t)N * E;           // vq_feat [N,E]       8 MB
    float* out2 = out1 + (size_t)N * E;           // one_hot [N,K]      16 MB
    float* out3 = out2 + (size_t)N * KCB;         // decoded [N,F]      64 MB
    float* out4 = out3 + (size_t)N * F;           // emb copy [K,E]      2 MB

    // ---- arena inside out3 (64 MB); dead before the fc2 writes reach it
    char* arena = (char*)out3;
    const size_t MB = 1024 * 1024;
    float* qb     = (float*)(arena + 0 * MB);     // [0,8)
    bf16*  khi    = (bf16*) (arena + 8 * MB);     // [8,12)
    bf16*  klo    = (bf16*) (arena + 12 * MB);    // [12,16)
    bf16*  vthi   = (bf16*) (arena + 16 * MB);    // [16,20)
    bf16*  vtlo   = (bf16*) (arena + 20 * MB);    // [20,24)
    float* ctx    = (float*)(arena + 24 * MB);    // [24,32)
    float* Op     = (float*)(arena + 32 * MB);    // [32,64): 512 x 16384 f32 partials
    float* decout = (float*)(arena + 56 * MB);    // [56,64): written after Op dead
    float* x1     = (float*)(arena + 16 * MB);    // reuse KV region after attention
    float* hb     = (float*)(arena + 8 * MB);
    float* ml     = (float*)out4;                 // 512 KB in emb-copy region (dead until end)
    float* embn   = out1;                         // dead until vq_select
    float* stage  = (float*)out4;                 // fc2 staging (after ml dead)

    EncW ew = { (const float*)d_in[1],  (const float*)d_in[2],  (const float*)d_in[3],
                (const float*)d_in[4],  (const float*)d_in[5],  (const float*)d_in[6],
                (const float*)d_in[7],  (const float*)d_in[8],  (const float*)d_in[9],
                (const float*)d_in[10], (const float*)d_in[11], (const float*)d_in[12],
                (const float*)d_in[13], (const float*)d_in[14], (const float*)d_in[15],
                (const float*)d_in[16] };
    EncW dw = { (const float*)d_in[17], (const float*)d_in[18], (const float*)d_in[19],
                (const float*)d_in[20], (const float*)d_in[21], (const float*)d_in[22],
                (const float*)d_in[23], (const float*)d_in[24], (const float*)d_in[25],
                (const float*)d_in[26], (const float*)d_in[27], (const float*)d_in[28],
                (const float*)d_in[29], (const float*)d_in[30], (const float*)d_in[31],
                (const float*)d_in[32] };

    // ---- phase E: encoder -> ctx
    normalize_emb<<<KCB, 256, 0, stream>>>(emb, embn);
    run_encoder_g3(stream, x_in, ew, qb, khi, klo, vthi, vtlo, ctx, Op, ml, x1, hb, ctx);

    // ---- phase F: fc1 -> encoded (out0)
    gemm3<64, false, false, true, false><<<dim3(4, 64), 256, 0, stream>>>(
        ctx, fc1_w, fc1_b, out0, nullptr, nullptr, D, D, E, E, 1.f);

    // ---- phase V: sims = encoded @ embn^T into out2; argmax -> one-hot + gather
    gemm3<128, false, false, false, false><<<dim3(8, 32), 256, 0, stream>>>(
        out0, embn, nullptr, out2, nullptr, nullptr, E, E, E, KCB, 1.f);
    vq_select_onehot<<<N, 256, 0, stream>>>(out2, emb, out1);

    // ---- phase D: decoder -> decout [56,64)
    run_encoder_g3(stream, out1, dw, qb, khi, klo, vthi, vtlo, ctx, Op, ml, x1, hb, decout);

    // ---- phase G: fc2 + relu (B natural). Rows [0,3584) write [0,56M) (disjoint
    // from decout); rows [3584,4096) read a staged copy since their writes cover decout.
    hipMemcpyAsync(stage, decout + (size_t)3584 * D, (size_t)512 * D * sizeof(float),
                   hipMemcpyDeviceToDevice, stream);
    gemm3<128, true, false, true, false><<<dim3(F / 128, 3584 / 128), 256, 0, stream>>>(
        decout, fc2_w, fc2_b, out3, nullptr, nullptr, D, D, F, F, 1.f);
    gemm3<128, true, false, true, false><<<dim3(F / 128, 512 / 128), 256, 0, stream>>>(
        stage, fc2_w, fc2_b, out3 + (size_t)3584 * F, nullptr, nullptr, D, D, F, F, 1.f);

    // ---- emb copy last (out4 was ml/staging)
    hipMemcpyAsync(out4, emb, (size_t)KCB * E * sizeof(float), hipMemcpyDeviceToDevice, stream);
}